// Round 1
// baseline (196.358 us; speedup 1.0000x reference)
//
#include <hip/hip_runtime.h>
#include <hip/hip_bf16.h>

typedef __bf16 bf16;
typedef __bf16 bf16x8 __attribute__((ext_vector_type(8)));
typedef float f32x4 __attribute__((ext_vector_type(4)));

#define S_TOK 4096   // S*B
#define D_DIM 1024
#define NBLK 8
#define BDIM 128
#define E_DIM 768
#define NH 12
#define HD 64
#define QKVW 2304    // 3*E
#define PADW 2312    // QKVW + 8 bf16 pad (breaks LDS bank alias at 4608B stride)

// ---------------- K0: weight prep (transpose + bf16 cast) ----------------
// wcatT[n][j][k] = {wq|wk|wv}[n][k][j']   (B^T layout, k contiguous)
// wfinT[n][d][e] = w_final[n][e][d]
__global__ __launch_bounds__(256) void prep_weights(
    const float* __restrict__ wq, const float* __restrict__ wk,
    const float* __restrict__ wv, const float* __restrict__ wfin,
    bf16* __restrict__ wcatT, bf16* __restrict__ wfinT) {
  long idx = (long)blockIdx.x * 256 + threadIdx.x;
  const long NCAT = (long)NBLK * QKVW * BDIM;  // 2359296
  if (idx < NCAT) {
    int k = idx & (BDIM - 1);
    long rem = idx >> 7;           // n*QKVW + j
    int j = (int)(rem % QKVW);
    int n = (int)(rem / QKVW);
    const float* src; int jj;
    if (j < 768) { src = wq; jj = j; }
    else if (j < 1536) { src = wk; jj = j - 768; }
    else { src = wv; jj = j - 1536; }
    float v = src[((long)n * BDIM + k) * E_DIM + jj];
    wcatT[idx] = (bf16)v;
  } else {
    long i2 = idx - NCAT;          // over 8*128*768 = 786432
    if (i2 < (long)NBLK * BDIM * E_DIM) {
      int e = (int)(i2 % E_DIM);
      long rem = i2 / E_DIM;
      int d = (int)(rem & (BDIM - 1));
      int n = (int)(rem >> 7);
      float v = wfin[((long)n * E_DIM + e) * BDIM + d];
      wfinT[i2] = (bf16)v;
    }
  }
}

// ---------------- K1: competition gating ----------------
// xg[n][tok][k] = x[tok][n*128+k] * softmax_n(comp_logits)[n]   (bf16)
__global__ __launch_bounds__(256) void gate_kernel(
    const float* __restrict__ x, const float* __restrict__ wcomp,
    bf16* __restrict__ xg) {
  int tok = blockIdx.x;
  int t = threadIdx.x;
  int n = t >> 5;          // block 0..7 (32 lanes each)
  int l = t & 31;
  const float* xrow = x + (long)tok * D_DIM + n * BDIM;
  float xv[4]; float part = 0.f;
#pragma unroll
  for (int i = 0; i < 4; ++i) {
    int d = l + i * 32;
    xv[i] = xrow[d];
    part += xv[i] * wcomp[n * BDIM + d];
  }
#pragma unroll
  for (int m = 16; m >= 1; m >>= 1) part += __shfl_xor(part, m, 64);
  __shared__ float logits[NBLK];
  __shared__ float comp[NBLK];
  if (l == 0) logits[n] = part;
  __syncthreads();
  if (t == 0) {
    float mx = logits[0];
#pragma unroll
    for (int i = 1; i < 8; ++i) mx = fmaxf(mx, logits[i]);
    float s = 0.f, e[8];
#pragma unroll
    for (int i = 0; i < 8; ++i) { e[i] = __expf(logits[i] - mx); s += e[i]; }
    float inv = 1.f / s;
#pragma unroll
    for (int i = 0; i < 8; ++i) comp[i] = e[i] * inv;
  }
  __syncthreads();
  float c = comp[n];
  bf16* dst = xg + ((long)n * S_TOK + tok) * BDIM;
#pragma unroll
  for (int i = 0; i < 4; ++i) dst[l + i * 32] = (bf16)(xv[i] * c);
}

// ---------------- shared GEMM machinery (m97 structure) ----------------
// Stages a 128x128 bf16 tile (rows rstride bytes apart; 256B of data per row)
// via global_load_lds width-16. LDS dest linear; global source pre-XOR-swizzled
// (chunk ^= row&7) so ds_read side can de-swizzle (m173/T2 pattern).
__device__ __forceinline__ void stage_tile(char* lds, const char* g, long rstride) {
  int wave = threadIdx.x >> 6, lane = threadIdx.x & 63;
#pragma unroll
  for (int s = 0; s < 8; ++s) {
    int instr = wave * 8 + s;               // 0..31, 1KB each
    int row = instr * 4 + (lane >> 4);      // 0..127
    int chunk = (lane & 15) ^ (row & 7);    // pre-swizzled source chunk
    const char* src = g + (long)row * rstride + chunk * 16;
    __builtin_amdgcn_global_load_lds(
        (const __attribute__((address_space(1))) void*)src,
        (__attribute__((address_space(3))) void*)(lds + instr * 1024), 16, 0, 0);
  }
}

// lane's 16B fragment: G[row][kchunk*8 .. +8) (kchunk = k/8)
__device__ __forceinline__ bf16x8 ld_frag(const char* lds, int row, int kchunk) {
  int chunk = kchunk ^ (row & 7);
  return *(const bf16x8*)(lds + row * 256 + chunk * 16);
}

// 4 waves, each computes a 64x64 quadrant as 4x4 frags of 16x16x32 MFMA.
// Consumes one staged K=128 slab: 4 k-steps of 32.
__device__ __forceinline__ void mfma_slab(const char* ldsA, const char* ldsB,
                                          f32x4 acc[4][4], int wm, int wn, int lane) {
#pragma unroll
  for (int ks = 0; ks < 4; ++ks) {
    int kchunk = ks * 4 + (lane >> 4);
    bf16x8 af[4], bfr[4];
#pragma unroll
    for (int i = 0; i < 4; ++i) af[i] = ld_frag(ldsA, wm + i * 16 + (lane & 15), kchunk);
#pragma unroll
    for (int j = 0; j < 4; ++j) bfr[j] = ld_frag(ldsB, wn + j * 16 + (lane & 15), kchunk);
#pragma unroll
    for (int i = 0; i < 4; ++i)
#pragma unroll
      for (int j = 0; j < 4; ++j)
        acc[i][j] = __builtin_amdgcn_mfma_f32_16x16x32_bf16(af[i], bfr[j], acc[i][j], 0, 0, 0);
  }
}

// ---------------- K2: QKV block GEMM ----------------
// per blk n: qkv_local[m][n][j] = xg_n[t0+m][:] @ Wcat_n[:][j]   (K=128, one slab)
__global__ __launch_bounds__(256) void qkv_gemm(
    const bf16* __restrict__ xg, const bf16* __restrict__ wcatT,
    bf16* __restrict__ qkv, int t0) {
  __shared__ char ldsA[32768];
  __shared__ char ldsB[32768];
  int nt = blockIdx.x;    // 0..17
  int mt = blockIdx.y;
  int blk = blockIdx.z;
  const char* Ab = (const char*)(xg + ((long)blk * S_TOK + t0 + mt * 128) * BDIM);
  const char* Bb = (const char*)(wcatT + ((long)blk * QKVW + nt * 128) * BDIM);
  stage_tile(ldsA, Ab, 256);
  stage_tile(ldsB, Bb, 256);
  __syncthreads();
  int wave = threadIdx.x >> 6, lane = threadIdx.x & 63;
  int wm = (wave >> 1) * 64, wn = (wave & 1) * 64;
  f32x4 acc[4][4] = {};
  mfma_slab(ldsA, ldsB, acc, wm, wn, lane);
  int rbase = (lane >> 4) * 4;
  int cb = lane & 15;
  long tokl0 = (long)mt * 128;
#pragma unroll
  for (int i = 0; i < 4; ++i) {
#pragma unroll
    for (int r = 0; r < 4; ++r) {
      long tokl = tokl0 + wm + i * 16 + rbase + r;
      bf16* dst = qkv + tokl * (NBLK * QKVW) + (long)blk * QKVW + nt * 128 + wn + cb;
#pragma unroll
      for (int j = 0; j < 4; ++j) dst[j * 16] = (bf16)acc[i][j][r];
    }
  }
}

// ---------------- K3: block-axis attention (one token per workgroup) ----------------
__global__ __launch_bounds__(256) void attn_kernel(
    const bf16* __restrict__ qkv, bf16* __restrict__ attn_out,
    float* __restrict__ out2, int t0, int TC) {
  __shared__ short qlds[NBLK * PADW];   // bf16 bits
  __shared__ float smp[4][64];
  int tl = blockIdx.x;
  long tok = t0 + tl;
  int t = threadIdx.x;
  // stage this token's qkv rows (8 x 2304 bf16) with per-block pad
  const uint4* src = (const uint4*)(qkv + (long)tl * NBLK * QKVW);
#pragma unroll
  for (int i = 0; i < 9; ++i) {
    int c = t + i * 256;           // 16B chunk 0..2303
    int n = c / 288;               // 288 chunks per block row
    int w = c - n * 288;
    *(uint4*)(&qlds[n * PADW + w * 8]) = src[c];
  }
  __syncthreads();
  int wave = t >> 6, lane = t & 63;
  int n = lane >> 3, mo = lane & 7;   // (row n, col m) for scores; (n, d-chunk) for PV
  const bf16* lds = (const bf16*)qlds;
  float smacc = 0.f;
#pragma unroll
  for (int hi = 0; hi < 3; ++hi) {
    int h = wave + hi * 4;
    // score[n][mo] = 0.125 * q[n]·k[mo]
    float s = 0.f;
#pragma unroll
    for (int dd = 0; dd < 8; ++dd) {
      bf16x8 q8 = *(const bf16x8*)(lds + n * PADW + h * HD + dd * 8);
      bf16x8 k8 = *(const bf16x8*)(lds + mo * PADW + 768 + h * HD + dd * 8);
#pragma unroll
      for (int u = 0; u < 8; ++u) s += (float)q8[u] * (float)k8[u];
    }
    s *= 0.125f;
    float mx = s;
#pragma unroll
    for (int msk = 1; msk < 8; msk <<= 1) mx = fmaxf(mx, __shfl_xor(mx, msk, 64));
    float p = __expf(s - mx);
    float sum = p;
#pragma unroll
    for (int msk = 1; msk < 8; msk <<= 1) sum += __shfl_xor(sum, msk, 64);
    float a = p / sum;
    smacc += a;
    // PV: out[n][h][mo*8..+8) = sum_m attn[n][m] * v[m][h][mo*8..+8)
    float o[8] = {};
#pragma unroll
    for (int m = 0; m < 8; ++m) {
      float am = __shfl(a, (lane & 56) | m, 64);
      bf16x8 v8 = *(const bf16x8*)(lds + m * PADW + 1536 + h * HD + mo * 8);
#pragma unroll
      for (int u = 0; u < 8; ++u) o[u] += am * (float)v8[u];
    }
    bf16x8 ov;
#pragma unroll
    for (int u = 0; u < 8; ++u) ov[u] = (bf16)o[u];
    *(bf16x8*)(attn_out + ((long)n * TC + tl) * E_DIM + h * HD + mo * 8) = ov;
  }
  smp[wave][lane] = smacc;
  __syncthreads();
  if (t < 64) {
    float v = (smp[0][t] + smp[1][t] + smp[2][t] + smp[3][t]) * (1.f / 12.f);
    out2[tok * 64 + t] = v;
  }
}

// ---------------- K4: final block GEMM ----------------
// out[t0+m][blk*128+d] = attn_out_blk[m][:] @ w_final_blk[:][d]   (K=768, 6 slabs)
__global__ __launch_bounds__(256) void final_gemm(
    const bf16* __restrict__ attn_out, const bf16* __restrict__ wfinT,
    float* __restrict__ out, int t0, int TC) {
  __shared__ char ldsA[32768];
  __shared__ char ldsB[32768];
  int mt = blockIdx.y;
  int blk = blockIdx.z;
  int wave = threadIdx.x >> 6, lane = threadIdx.x & 63;
  int wm = (wave >> 1) * 64, wn = (wave & 1) * 64;
  f32x4 acc[4][4] = {};
  const char* Abase = (const char*)(attn_out + ((long)blk * TC + mt * 128) * E_DIM);
  const char* Bbase = (const char*)(wfinT + (long)blk * BDIM * E_DIM);
  for (int kt = 0; kt < 6; ++kt) {
    stage_tile(ldsA, Abase + kt * 256, E_DIM * 2);
    stage_tile(ldsB, Bbase + kt * 256, E_DIM * 2);
    __syncthreads();
    mfma_slab(ldsA, ldsB, acc, wm, wn, lane);
    __syncthreads();
  }
  int rbase = (lane >> 4) * 4;
  int cb = lane & 15;
#pragma unroll
  for (int i = 0; i < 4; ++i) {
#pragma unroll
    for (int r = 0; r < 4; ++r) {
      long tok = (long)t0 + mt * 128 + wm + i * 16 + rbase + r;
      float* dst = out + tok * D_DIM + blk * BDIM + wn + cb;
#pragma unroll
      for (int j = 0; j < 4; ++j) dst[j * 16] = acc[i][j][r];
    }
  }
}

// ---------------- launcher ----------------
extern "C" void kernel_launch(void* const* d_in, const int* in_sizes, int n_in,
                              void* d_out, int out_size, void* d_ws, size_t ws_size,
                              hipStream_t stream) {
  const float* x     = (const float*)d_in[0];
  const float* wcomp = (const float*)d_in[1];
  const float* wq    = (const float*)d_in[2];
  const float* wk    = (const float*)d_in[3];
  const float* wv    = (const float*)d_in[4];
  const float* wfin  = (const float*)d_in[5];
  float* out  = (float*)d_out;
  float* out2 = out + (long)S_TOK * D_DIM;   // score_mean [4096][8][8]

  char* ws = (char*)d_ws;
  bf16* xg    = (bf16*)ws;                                  // 8,388,608 B
  bf16* wcatT = (bf16*)(ws + 8388608);                      // 4,718,592 B
  bf16* wfinT = (bf16*)(ws + 8388608 + 4718592);            // 1,572,864 B
  char* dyn   = ws + 14680064;
  // per-token scratch: qkv 36864 B + attn_out 12288 B
  long TC = (long)((ws_size > 14680064 ? ws_size - 14680064 : 0) / 49152);
  if (TC > S_TOK) TC = S_TOK;
  TC &= ~127L;
  if (TC < 128) TC = 128;   // hope: ws_size >= ~21 MB
  bf16* qkvb  = (bf16*)dyn;
  bf16* attnb = (bf16*)(dyn + TC * 36864L);

  prep_weights<<<12288, 256, 0, stream>>>(wq, wk, wv, wfin, wcatT, wfinT);
  gate_kernel<<<S_TOK, 256, 0, stream>>>(x, wcomp, xg);
  for (int t0 = 0; t0 < S_TOK; t0 += (int)TC) {
    int tc = S_TOK - t0; if (tc > TC) tc = (int)TC;
    dim3 g2(18, tc / 128, 8);
    qkv_gemm<<<g2, 256, 0, stream>>>(xg, wcatT, qkvb, t0);
    attn_kernel<<<tc, 256, 0, stream>>>(qkvb, attnb, out2, t0, tc);
    dim3 g4(1, tc / 128, 8);
    final_gemm<<<g4, 256, 0, stream>>>(attnb, wfinT, out, t0, tc);
  }
}